// Round 17
// baseline (123.375 us; speedup 1.0000x reference)
//
#include <hip/hip_runtime.h>

#define DIM 4096
#define HD 128
#define NQH 32
#define NKVH 8
#define NB 8
#define MAXSEQ 4096
#define TOTALT 4096          // start_pos + 1 (start_pos fixed 4095)
#define QCOLS (NQH*HD)       // 4096
#define KVCOLS (NKVH*HD)     // 1024
#define CCOLS (QCOLS + 2*KVCOLS) // 6144
#define DCH 64               // split-K d-chunk
#define KSP (DIM/DCH)        // 64
#define SUB 32               // rows per sub-tile
#define NSUB 16              // sub-tiles per block
#define CHK (SUB*NSUB)       // 512 rows per block
#define NCHB (TOTALT/CHK)    // 8 chunks per (b,kvh)

typedef __attribute__((address_space(1))) const void __gvoid;
typedef __attribute__((address_space(3))) void __lvoid;
// native vector type for __builtin_nontemporal_load (HIP_vector_type rejected)
typedef float nfloat4 __attribute__((ext_vector_type(4)));
// aux=2 = NT (non-temporal): K/V lines not retained in L2/L3 -> stream from
// HBM (~6.3 TB/s) instead of Infinity-Cache hit path (~3.3 TB/s measured cap).
// [r15: this one bit took total 119.9 -> 97.2 us]
#define GLD16NT(g, l) __builtin_amdgcn_global_load_lds((__gvoid*)(g), (__lvoid*)(l), 16, 0, 2)
#define VMWAIT(N) asm volatile("s_waitcnt vmcnt(" #N ")" ::: "memory")
#define LGKMWAIT0 asm volatile("s_waitcnt lgkmcnt(0)" ::: "memory")
#define SCHEDBAR __builtin_amdgcn_sched_barrier(0)

// ---------------------------------------------------------------------------
// Fused GEMV partials. 128 threads, 512 cols/block (4/thread, float4 loads).
// r16/r17: weight reads are NON-TEMPORAL — single-use per launch; with K/V
// now NT, weights (192 MB) would become L3-resident and replays would read
// them through the slow (~3.3 TB/s) L3-hit path instead of HBM streaming.
// ---------------------------------------------------------------------------
__global__ __launch_bounds__(128) void gemv4_kernel(
    const float* __restrict__ x, const float* __restrict__ wq,
    const float* __restrict__ wk, const float* __restrict__ wv,
    float* __restrict__ part, int pstride)
{
    __shared__ float xs[DCH*NB];       // [d][b]
    const int tx = threadIdx.x;
    const int d0 = blockIdx.y*DCH;
    for (int i = tx; i < DCH*NB; i += 128)          // i = b*64 + d
        xs[(i&63)*NB + (i>>6)] = x[(i>>6)*DIM + d0 + (i&63)];
    __syncthreads();

    const int colbase = blockIdx.x*512;
    const float* w; int wcols, wcol;
    if (colbase < QCOLS)               { w = wq; wcols = QCOLS;  wcol = colbase; }
    else if (colbase < QCOLS+KVCOLS)   { w = wk; wcols = KVCOLS; wcol = colbase - QCOLS; }
    else                               { w = wv; wcols = KVCOLS; wcol = colbase - QCOLS - KVCOLS; }

    const float* wp = w + (size_t)d0*wcols + wcol + tx*4;
    float4 a[NB];
    #pragma unroll
    for (int b = 0; b < NB; b++) { a[b].x=0.f; a[b].y=0.f; a[b].z=0.f; a[b].w=0.f; }

    #pragma unroll 4
    for (int dl = 0; dl < DCH; dl++) {
        nfloat4 wv4 = __builtin_nontemporal_load(
            reinterpret_cast<const nfloat4*>(wp + (size_t)dl*wcols));
        float4 x0 = *reinterpret_cast<const float4*>(&xs[dl*NB]);
        float4 x1 = *reinterpret_cast<const float4*>(&xs[dl*NB + 4]);
        a[0].x += wv4.x*x0.x; a[0].y += wv4.y*x0.x; a[0].z += wv4.z*x0.x; a[0].w += wv4.w*x0.x;
        a[1].x += wv4.x*x0.y; a[1].y += wv4.y*x0.y; a[1].z += wv4.z*x0.y; a[1].w += wv4.w*x0.y;
        a[2].x += wv4.x*x0.z; a[2].y += wv4.y*x0.z; a[2].z += wv4.z*x0.z; a[2].w += wv4.w*x0.z;
        a[3].x += wv4.x*x0.w; a[3].y += wv4.y*x0.w; a[3].z += wv4.z*x0.w; a[3].w += wv4.w*x0.w;
        a[4].x += wv4.x*x1.x; a[4].y += wv4.y*x1.x; a[4].z += wv4.z*x1.x; a[4].w += wv4.w*x1.x;
        a[5].x += wv4.x*x1.y; a[5].y += wv4.y*x1.y; a[5].z += wv4.z*x1.y; a[5].w += wv4.w*x1.y;
        a[6].x += wv4.x*x1.z; a[6].y += wv4.y*x1.z; a[6].z += wv4.z*x1.z; a[6].w += wv4.w*x1.z;
        a[7].x += wv4.x*x1.w; a[7].y += wv4.y*x1.w; a[7].z += wv4.z*x1.w; a[7].w += wv4.w*x1.w;
    }
    const int ocol = colbase + tx*4;
    #pragma unroll
    for (int b = 0; b < NB; b++)
        *reinterpret_cast<float4*>(&part[((size_t)(blockIdx.y*NB + b))*pstride + ocol]) = a[b];
}

// ---------------------------------------------------------------------------
// Reduce QKV split-K partials (float2) + RoPE on q,k.
// ---------------------------------------------------------------------------
__global__ __launch_bounds__(256) void qkv_reduce_rope(
    const float* __restrict__ part, const float* __restrict__ fc,
    const float* __restrict__ fs, float* __restrict__ q,
    float* __restrict__ knew, float* __restrict__ vnew)
{
    const int p = blockIdx.x*256 + threadIdx.x;   // 0 .. NB*CCOLS/2-1
    const int b = p / (CCOLS/2);
    const int c0 = (p % (CCOLS/2))*2;
    float s0 = 0.f, s1 = 0.f;
    const float* pb = part + (size_t)b*CCOLS + c0;
    #pragma unroll 8
    for (int ky = 0; ky < KSP; ky++) {
        float2 v = *reinterpret_cast<const float2*>(pb + (size_t)ky*NB*CCOLS);
        s0 += v.x; s1 += v.y;
    }
    float r0 = s0, r1 = s1;
    if (c0 < QCOLS + KVCOLS) {           // q or k: rope
        int i = (c0 & (HD-1)) >> 1;
        float c = fc[i], s = fs[i];
        r0 = s0*c - s1*s;
        r1 = s0*s + s1*c;
    }
    if (c0 < QCOLS) {
        *reinterpret_cast<float2*>(&q[b*QCOLS + c0]) = make_float2(r0, r1);
    } else if (c0 < QCOLS + KVCOLS) {
        *reinterpret_cast<float2*>(&knew[b*KVCOLS + (c0 - QCOLS)]) = make_float2(r0, r1);
    } else {
        *reinterpret_cast<float2*>(&vnew[b*KVCOLS + (c0 - QCOLS - KVCOLS)]) = make_float2(r0, r1);
    }
}

// ---------------------------------------------------------------------------
// Streaming flash-decode v4-NT (r15, proven): no-max softmax, counted-vmcnt
// two-barrier pipeline, NT K/V staging, wave-private psf, split-row PV.
// ---------------------------------------------------------------------------
__global__ __launch_bounds__(256) void attn_stream_kernel(
    const float* __restrict__ q, const float* __restrict__ knew,
    const float* __restrict__ vnew, const float* __restrict__ K,
    const float* __restrict__ V, float* __restrict__ pout,
    float* __restrict__ pml)
{
    __shared__ float ks[2][SUB*HD];            // 2 x 16 KB, swizzled rows
    __shared__ float vs_[2][SUB*HD];           // 2 x 16 KB, linear
    __shared__ __align__(16) float psf[SUB*4]; // 512 B  [row][head]
    __shared__ float ps2[16*HD];               // 8 KB epilogue combine

    const int tx = threadIdx.x;
    const int chunk = blockIdx.x, kvh = blockIdx.y, b = blockIdx.z;
    const size_t blkid = (size_t)(b*NKVH + kvh)*NCHB + chunk;
    const int lane = tx & 63, j = tx >> 6;
    const int r = lane & 31, h = lane >> 5;
    const size_t kvstride = (size_t)NKVH*HD;
    const size_t kbase0 = ((size_t)(b*MAXSEQ + chunk*CHK)*NKVH + kvh)*HD;
    const bool lastChunk = (chunk == NCHB-1);
    const int wseg = (tx & 192)*4;    // wave-uniform float offset of wave's segment

    auto stage = [&](int nb, int srow, bool lastT) {
        #pragma unroll
        for (int k = 0; k < 4; k++) {
            int F = k*256 + tx;            // float4 slot
            int t = F >> 5, sw = F & 31;
            int i = sw ^ t;                // K pre-swizzle: LDS(t,sw) <- gcol sw^t
            const float* srck = (lastT && t == SUB-1)
                ? (knew + (b*NKVH + kvh)*HD + i*4)
                : (K + kbase0 + (size_t)(srow + t)*kvstride + i*4);
            GLD16NT(srck, &ks[nb][k*1024 + wseg]);
            const float* srcv = (lastT && t == SUB-1)
                ? (vnew + (b*NKVH + kvh)*HD + sw*4)
                : (V + kbase0 + (size_t)(srow + t)*kvstride + sw*4);
            GLD16NT(srcv, &vs_[nb][k*1024 + wseg]);
        }
    };

    // prologue: q d-half -> registers (16 float4; these 16 vmcnt entries are
    // retired by the s=0 VMWAIT(8) together with tile-0's 8, FIFO order).
    float4 qreg[16];
    {
        const float4* qg = reinterpret_cast<const float4*>(
            q + b*QCOLS + (kvh*4 + j)*HD + h*64);
        #pragma unroll
        for (int c = 0; c < 16; c++) qreg[c] = qg[c];
    }
    stage(0, 0, false);               // tile 0 in flight (never the last tile)

    float2 acc[4];                    // [head], rows [8j,8j+8), lane = d-pair
    #pragma unroll
    for (int hh = 0; hh < 4; hh++) acc[hh] = make_float2(0.f, 0.f);
    float l_lane = 0.f;

    for (int s = 0; s < NSUB; ++s) {
        const int cb = s & 1;
        if (s+1 < NSUB) {
            stage(cb^1, (s+1)*SUB, lastChunk && (s+1 == NSUB-1));
            VMWAIT(8);                // tile-s (and q at s=0) done; s+1 in flight
        } else {
            VMWAIT(0);
        }
        __builtin_amdgcn_s_barrier(); // BAR_A
        SCHEDBAR;

        // phase 1: score(head j, row r), d-half h; q in registers
        float sj = 0.f;
        {
            const float* kc = ks[cb];
            #pragma unroll
            for (int c = 0; c < 16; c++) {
                int i = h*16 + c;
                float4 kv = *reinterpret_cast<const float4*>(&kc[(r*32 + (i ^ r))*4]);
                float4 qv = qreg[c];
                sj += kv.x*qv.x + kv.y*qv.y + kv.z*qv.z + kv.w*qv.w;
            }
        }
        sj += __shfl_xor(sj, 32, 64);      // combine d-halves
        sj *= 0.08838834764831845f;        // 1/sqrt(128)
        float p = __expf(sj);              // no max subtraction (safe: |s|<~10)
        l_lane += p;
        if (h == 0) psf[r*4 + j] = p;
        LGKMWAIT0; SCHEDBAR;
        __builtin_amdgcn_s_barrier();      // BAR_B: psf ready
        SCHEDBAR;

        // phase 3: wave j owns rows [8j,8j+8), all 4 heads; lane = d-pair
        {
            const float* vc = vs_[cb];
            #pragma unroll
            for (int t = 0; t < 8; t++) {
                int row = j*8 + t;
                float4 pg = *reinterpret_cast<const float4*>(&psf[row*4]);
                float2 vv = *reinterpret_cast<const float2*>(&vc[row*HD + lane*2]);
                acc[0].x += pg.x*vv.x; acc[0].y += pg.x*vv.y;
                acc[1].x += pg.y*vv.x; acc[1].y += pg.y*vv.y;
                acc[2].x += pg.z*vv.x; acc[2].y += pg.z*vv.y;
                acc[3].x += pg.w*vv.x; acc[3].y += pg.w*vv.y;
            }
        }
        LGKMWAIT0; SCHEDBAR;
        __builtin_amdgcn_s_barrier();      // BAR_C: buffers free for re-stage
        SCHEDBAR;
    }

    // epilogue: cross-wave combine via ps2 (once)
    #pragma unroll
    for (int hh = 0; hh < 4; hh++)
        *reinterpret_cast<float2*>(&ps2[(j*4 + hh)*HD + lane*2]) = acc[hh];
    // l: masks <32 keep exchanges within each 32-half (h=1 half holds
    // duplicate copies, never mixed in) -> lane 0 = sum over rows 0..31.
    #pragma unroll
    for (int k = 16; k >= 1; k >>= 1) l_lane += __shfl_xor(l_lane, k, 64);
    if (lane == 0) pml[blkid*4 + j] = l_lane;
    __syncthreads();
    {
        const int hh = tx >> 6;
        const int d0 = (tx & 63)*2;
        float sx = 0.f, sy = 0.f;
        #pragma unroll
        for (int w = 0; w < 4; w++) {
            float2 v = *reinterpret_cast<const float2*>(&ps2[(w*4 + hh)*HD + d0]);
            sx += v.x; sy += v.y;
        }
        *reinterpret_cast<float2*>(pout + blkid*512 + hh*HD + d0) = make_float2(sx, sy);
    }
}

// ---------------------------------------------------------------------------
// Combine across NCHB chunks (no-max softmax: plain sums).
// ---------------------------------------------------------------------------
__global__ __launch_bounds__(128) void attn_combine_kernel(
    const float* __restrict__ pout, const float* __restrict__ pml,
    float* __restrict__ attn_out)
{
    const int d = threadIdx.x;
    const int qh = blockIdx.x;
    const int b = blockIdx.y;
    const int kvh = qh >> 2, j = qh & 3;
    const size_t base = (size_t)(b*NKVH + kvh)*NCHB;
    float L = 0.f, acc = 0.f;
    #pragma unroll
    for (int i = 0; i < NCHB; i++) {
        L   += pml[(base + i)*4 + j];
        acc += pout[(base + i)*512 + j*HD + d];
    }
    attn_out[b*QCOLS + qh*HD + d] = acc / L;
}

// ---------------------------------------------------------------------------
// Final split-K reduce for wo (float2), f32 output.
// ---------------------------------------------------------------------------
__global__ __launch_bounds__(256) void wo_reduce_kernel(
    const float* __restrict__ part, float* __restrict__ out)
{
    const int g = blockIdx.x*256 + threadIdx.x;   // float2 index, 0..16383
    float sx = 0.f, sy = 0.f;
    #pragma unroll 8
    for (int ky = 0; ky < KSP; ky++) {
        float2 v = *reinterpret_cast<const float2*>(part + (size_t)ky*NB*QCOLS + g*2);
        sx += v.x; sy += v.y;
    }
    *reinterpret_cast<float2*>(out + g*2) = make_float2(sx, sy);
}

extern "C" void kernel_launch(void* const* d_in, const int* in_sizes, int n_in,
                              void* d_out, int out_size, void* d_ws, size_t ws_size,
                              hipStream_t stream)
{
    const float* x  = (const float*)d_in[0];
    // d_in[1] = start_pos (int scalar) = 4095, fixed by the problem.
    const float* fc = (const float*)d_in[2];
    const float* fs = (const float*)d_in[3];
    const float* wq = (const float*)d_in[4];
    const float* wk = (const float*)d_in[5];
    const float* wv = (const float*)d_in[6];
    const float* wo = (const float*)d_in[7];
    const float* K  = (const float*)d_in[8];
    const float* V  = (const float*)d_in[9];

    float* ws     = (float*)d_ws;
    float* q      = ws;                     // 32768
    float* knew   = ws + 32768;             // 8192
    float* vnew   = ws + 40960;             // 8192
    float* attn_o = ws + 49152;             // 32768
    float* qkvp   = ws + 81920;             // 64*8*6144 = 3,145,728
    float* pout   = ws + 3227648;           // 512*512   = 262,144
    float* pml    = ws + 3489792;           // 512*4     = 2,048
    float* wop    = ws + 81920;             // aliases qkvp (time-disjoint)

    // 1. fused QKV projection partials (768 blocks = 3/CU even; NT weights)
    gemv4_kernel<<<dim3(CCOLS/512, KSP), dim3(128), 0, stream>>>(x, wq, wk, wv, qkvp, CCOLS);
    // 2. reduce + RoPE
    qkv_reduce_rope<<<dim3(NB*CCOLS/2/256), dim3(256), 0, stream>>>(qkvp, fc, fs, q, knew, vnew);
    // 3. streaming flash-decode v4-NT (non-temporal K/V)
    attn_stream_kernel<<<dim3(NCHB, NKVH, NB), dim3(256), 0, stream>>>(q, knew, vnew, K, V, pout, pml);
    // 4. combine (plain sums)
    attn_combine_kernel<<<dim3(NQH, NB), dim3(128), 0, stream>>>(pout, pml, attn_o);
    // 5. output projection partials (512 blocks = 2/CU even; NT weights)
    gemv4_kernel<<<dim3(QCOLS/512, KSP), dim3(128), 0, stream>>>(attn_o, wo, wo, wo, wop, QCOLS);
    // 6. final reduce, f32 out
    wo_reduce_kernel<<<dim3(NB*QCOLS/2/256), dim3(256), 0, stream>>>(wop, (float*)d_out);
}

// Round 18
// 97.103 us; speedup vs baseline: 1.2706x; 1.2706x over previous
//
#include <hip/hip_runtime.h>

#define DIM 4096
#define HD 128
#define NQH 32
#define NKVH 8
#define NB 8
#define MAXSEQ 4096
#define TOTALT 4096          // start_pos + 1 (start_pos fixed 4095)
#define QCOLS (NQH*HD)       // 4096
#define KVCOLS (NKVH*HD)     // 1024
#define CCOLS (QCOLS + 2*KVCOLS) // 6144
#define DCH 64               // split-K d-chunk
#define KSP (DIM/DCH)        // 64
#define SUB 32               // rows per sub-tile
#define NSUB 16              // sub-tiles per block
#define CHK (SUB*NSUB)       // 512 rows per block
#define NCHB (TOTALT/CHK)    // 8 chunks per (b,kvh)

typedef __attribute__((address_space(1))) const void __gvoid;
typedef __attribute__((address_space(3))) void __lvoid;
// aux=2 = NT (non-temporal): K/V lines not retained in L2/L3 -> stream from
// HBM while the L3 serves the (resident) weights — two parallel BW pools.
// [r15: this bit took total 119.9 -> 97.2 us. r17: NT on weights too = 123 us
//  (everything re-serialized on HBM). Keep NT on K/V ONLY.]
#define GLD16NT(g, l) __builtin_amdgcn_global_load_lds((__gvoid*)(g), (__lvoid*)(l), 16, 0, 2)
#define VMWAIT(N) asm volatile("s_waitcnt vmcnt(" #N ")" ::: "memory")
#define LGKMWAIT0 asm volatile("s_waitcnt lgkmcnt(0)" ::: "memory")
#define SCHEDBAR __builtin_amdgcn_sched_barrier(0)

// ---------------------------------------------------------------------------
// Fused GEMV partials. 128 threads, 512 cols/block (4/thread, float4 loads).
// Weight loads are NORMAL (cached): weights are L3-resident on replays and
// the L3 path runs in parallel with the NT'd K/V HBM stream (r17 lesson).
// ---------------------------------------------------------------------------
__global__ __launch_bounds__(128) void gemv4_kernel(
    const float* __restrict__ x, const float* __restrict__ wq,
    const float* __restrict__ wk, const float* __restrict__ wv,
    float* __restrict__ part, int pstride)
{
    __shared__ float xs[DCH*NB];       // [d][b]
    const int tx = threadIdx.x;
    const int d0 = blockIdx.y*DCH;
    for (int i = tx; i < DCH*NB; i += 128)          // i = b*64 + d
        xs[(i&63)*NB + (i>>6)] = x[(i>>6)*DIM + d0 + (i&63)];
    __syncthreads();

    const int colbase = blockIdx.x*512;
    const float* w; int wcols, wcol;
    if (colbase < QCOLS)               { w = wq; wcols = QCOLS;  wcol = colbase; }
    else if (colbase < QCOLS+KVCOLS)   { w = wk; wcols = KVCOLS; wcol = colbase - QCOLS; }
    else                               { w = wv; wcols = KVCOLS; wcol = colbase - QCOLS - KVCOLS; }

    const float* wp = w + (size_t)d0*wcols + wcol + tx*4;
    float4 a[NB];
    #pragma unroll
    for (int b = 0; b < NB; b++) { a[b].x=0.f; a[b].y=0.f; a[b].z=0.f; a[b].w=0.f; }

    #pragma unroll 4
    for (int dl = 0; dl < DCH; dl++) {
        float4 wv4 = *reinterpret_cast<const float4*>(wp + (size_t)dl*wcols);
        float4 x0 = *reinterpret_cast<const float4*>(&xs[dl*NB]);
        float4 x1 = *reinterpret_cast<const float4*>(&xs[dl*NB + 4]);
        a[0].x += wv4.x*x0.x; a[0].y += wv4.y*x0.x; a[0].z += wv4.z*x0.x; a[0].w += wv4.w*x0.x;
        a[1].x += wv4.x*x0.y; a[1].y += wv4.y*x0.y; a[1].z += wv4.z*x0.y; a[1].w += wv4.w*x0.y;
        a[2].x += wv4.x*x0.z; a[2].y += wv4.y*x0.z; a[2].z += wv4.z*x0.z; a[2].w += wv4.w*x0.z;
        a[3].x += wv4.x*x0.w; a[3].y += wv4.y*x0.w; a[3].z += wv4.z*x0.w; a[3].w += wv4.w*x0.w;
        a[4].x += wv4.x*x1.x; a[4].y += wv4.y*x1.x; a[4].z += wv4.z*x1.x; a[4].w += wv4.w*x1.x;
        a[5].x += wv4.x*x1.y; a[5].y += wv4.y*x1.y; a[5].z += wv4.z*x1.y; a[5].w += wv4.w*x1.y;
        a[6].x += wv4.x*x1.z; a[6].y += wv4.y*x1.z; a[6].z += wv4.z*x1.z; a[6].w += wv4.w*x1.z;
        a[7].x += wv4.x*x1.w; a[7].y += wv4.y*x1.w; a[7].z += wv4.z*x1.w; a[7].w += wv4.w*x1.w;
    }
    const int ocol = colbase + tx*4;
    #pragma unroll
    for (int b = 0; b < NB; b++)
        *reinterpret_cast<float4*>(&part[((size_t)(blockIdx.y*NB + b))*pstride + ocol]) = a[b];
}

// ---------------------------------------------------------------------------
// Reduce QKV split-K partials (float2) + RoPE on q,k.
// ---------------------------------------------------------------------------
__global__ __launch_bounds__(256) void qkv_reduce_rope(
    const float* __restrict__ part, const float* __restrict__ fc,
    const float* __restrict__ fs, float* __restrict__ q,
    float* __restrict__ knew, float* __restrict__ vnew)
{
    const int p = blockIdx.x*256 + threadIdx.x;   // 0 .. NB*CCOLS/2-1
    const int b = p / (CCOLS/2);
    const int c0 = (p % (CCOLS/2))*2;
    float s0 = 0.f, s1 = 0.f;
    const float* pb = part + (size_t)b*CCOLS + c0;
    #pragma unroll 8
    for (int ky = 0; ky < KSP; ky++) {
        float2 v = *reinterpret_cast<const float2*>(pb + (size_t)ky*NB*CCOLS);
        s0 += v.x; s1 += v.y;
    }
    float r0 = s0, r1 = s1;
    if (c0 < QCOLS + KVCOLS) {           // q or k: rope
        int i = (c0 & (HD-1)) >> 1;
        float c = fc[i], s = fs[i];
        r0 = s0*c - s1*s;
        r1 = s0*s + s1*c;
    }
    if (c0 < QCOLS) {
        *reinterpret_cast<float2*>(&q[b*QCOLS + c0]) = make_float2(r0, r1);
    } else if (c0 < QCOLS + KVCOLS) {
        *reinterpret_cast<float2*>(&knew[b*KVCOLS + (c0 - QCOLS)]) = make_float2(r0, r1);
    } else {
        *reinterpret_cast<float2*>(&vnew[b*KVCOLS + (c0 - QCOLS - KVCOLS)]) = make_float2(r0, r1);
    }
}

// ---------------------------------------------------------------------------
// Streaming flash-decode v4-NT (r15, proven best): no-max softmax,
// counted-vmcnt two-barrier pipeline, NT K/V staging, wave-private psf,
// split-row PV.
// ---------------------------------------------------------------------------
__global__ __launch_bounds__(256) void attn_stream_kernel(
    const float* __restrict__ q, const float* __restrict__ knew,
    const float* __restrict__ vnew, const float* __restrict__ K,
    const float* __restrict__ V, float* __restrict__ pout,
    float* __restrict__ pml)
{
    __shared__ float ks[2][SUB*HD];            // 2 x 16 KB, swizzled rows
    __shared__ float vs_[2][SUB*HD];           // 2 x 16 KB, linear
    __shared__ __align__(16) float psf[SUB*4]; // 512 B  [row][head]
    __shared__ float ps2[16*HD];               // 8 KB epilogue combine

    const int tx = threadIdx.x;
    const int chunk = blockIdx.x, kvh = blockIdx.y, b = blockIdx.z;
    const size_t blkid = (size_t)(b*NKVH + kvh)*NCHB + chunk;
    const int lane = tx & 63, j = tx >> 6;
    const int r = lane & 31, h = lane >> 5;
    const size_t kvstride = (size_t)NKVH*HD;
    const size_t kbase0 = ((size_t)(b*MAXSEQ + chunk*CHK)*NKVH + kvh)*HD;
    const bool lastChunk = (chunk == NCHB-1);
    const int wseg = (tx & 192)*4;    // wave-uniform float offset of wave's segment

    auto stage = [&](int nb, int srow, bool lastT) {
        #pragma unroll
        for (int k = 0; k < 4; k++) {
            int F = k*256 + tx;            // float4 slot
            int t = F >> 5, sw = F & 31;
            int i = sw ^ t;                // K pre-swizzle: LDS(t,sw) <- gcol sw^t
            const float* srck = (lastT && t == SUB-1)
                ? (knew + (b*NKVH + kvh)*HD + i*4)
                : (K + kbase0 + (size_t)(srow + t)*kvstride + i*4);
            GLD16NT(srck, &ks[nb][k*1024 + wseg]);
            const float* srcv = (lastT && t == SUB-1)
                ? (vnew + (b*NKVH + kvh)*HD + sw*4)
                : (V + kbase0 + (size_t)(srow + t)*kvstride + sw*4);
            GLD16NT(srcv, &vs_[nb][k*1024 + wseg]);
        }
    };

    // prologue: q d-half -> registers (16 float4; these 16 vmcnt entries are
    // retired by the s=0 VMWAIT(8) together with tile-0's 8, FIFO order).
    float4 qreg[16];
    {
        const float4* qg = reinterpret_cast<const float4*>(
            q + b*QCOLS + (kvh*4 + j)*HD + h*64);
        #pragma unroll
        for (int c = 0; c < 16; c++) qreg[c] = qg[c];
    }
    stage(0, 0, false);               // tile 0 in flight (never the last tile)

    float2 acc[4];                    // [head], rows [8j,8j+8), lane = d-pair
    #pragma unroll
    for (int hh = 0; hh < 4; hh++) acc[hh] = make_float2(0.f, 0.f);
    float l_lane = 0.f;

    for (int s = 0; s < NSUB; ++s) {
        const int cb = s & 1;
        if (s+1 < NSUB) {
            stage(cb^1, (s+1)*SUB, lastChunk && (s+1 == NSUB-1));
            VMWAIT(8);                // tile-s (and q at s=0) done; s+1 in flight
        } else {
            VMWAIT(0);
        }
        __builtin_amdgcn_s_barrier(); // BAR_A
        SCHEDBAR;

        // phase 1: score(head j, row r), d-half h; q in registers
        float sj = 0.f;
        {
            const float* kc = ks[cb];
            #pragma unroll
            for (int c = 0; c < 16; c++) {
                int i = h*16 + c;
                float4 kv = *reinterpret_cast<const float4*>(&kc[(r*32 + (i ^ r))*4]);
                float4 qv = qreg[c];
                sj += kv.x*qv.x + kv.y*qv.y + kv.z*qv.z + kv.w*qv.w;
            }
        }
        sj += __shfl_xor(sj, 32, 64);      // combine d-halves
        sj *= 0.08838834764831845f;        // 1/sqrt(128)
        float p = __expf(sj);              // no max subtraction (safe: |s|<~10)
        l_lane += p;
        if (h == 0) psf[r*4 + j] = p;
        LGKMWAIT0; SCHEDBAR;
        __builtin_amdgcn_s_barrier();      // BAR_B: psf ready
        SCHEDBAR;

        // phase 3: wave j owns rows [8j,8j+8), all 4 heads; lane = d-pair
        {
            const float* vc = vs_[cb];
            #pragma unroll
            for (int t = 0; t < 8; t++) {
                int row = j*8 + t;
                float4 pg = *reinterpret_cast<const float4*>(&psf[row*4]);
                float2 vv = *reinterpret_cast<const float2*>(&vc[row*HD + lane*2]);
                acc[0].x += pg.x*vv.x; acc[0].y += pg.x*vv.y;
                acc[1].x += pg.y*vv.x; acc[1].y += pg.y*vv.y;
                acc[2].x += pg.z*vv.x; acc[2].y += pg.z*vv.y;
                acc[3].x += pg.w*vv.x; acc[3].y += pg.w*vv.y;
            }
        }
        LGKMWAIT0; SCHEDBAR;
        __builtin_amdgcn_s_barrier();      // BAR_C: buffers free for re-stage
        SCHEDBAR;
    }

    // epilogue: cross-wave combine via ps2 (once)
    #pragma unroll
    for (int hh = 0; hh < 4; hh++)
        *reinterpret_cast<float2*>(&ps2[(j*4 + hh)*HD + lane*2]) = acc[hh];
    // l: masks <32 keep exchanges within each 32-half (h=1 half holds
    // duplicate copies, never mixed in) -> lane 0 = sum over rows 0..31.
    #pragma unroll
    for (int k = 16; k >= 1; k >>= 1) l_lane += __shfl_xor(l_lane, k, 64);
    if (lane == 0) pml[blkid*4 + j] = l_lane;
    __syncthreads();
    {
        const int hh = tx >> 6;
        const int d0 = (tx & 63)*2;
        float sx = 0.f, sy = 0.f;
        #pragma unroll
        for (int w = 0; w < 4; w++) {
            float2 v = *reinterpret_cast<const float2*>(&ps2[(w*4 + hh)*HD + d0]);
            sx += v.x; sy += v.y;
        }
        *reinterpret_cast<float2*>(pout + blkid*512 + hh*HD + d0) = make_float2(sx, sy);
    }
}

// ---------------------------------------------------------------------------
// Combine across NCHB chunks (no-max softmax: plain sums).
// ---------------------------------------------------------------------------
__global__ __launch_bounds__(128) void attn_combine_kernel(
    const float* __restrict__ pout, const float* __restrict__ pml,
    float* __restrict__ attn_out)
{
    const int d = threadIdx.x;
    const int qh = blockIdx.x;
    const int b = blockIdx.y;
    const int kvh = qh >> 2, j = qh & 3;
    const size_t base = (size_t)(b*NKVH + kvh)*NCHB;
    float L = 0.f, acc = 0.f;
    #pragma unroll
    for (int i = 0; i < NCHB; i++) {
        L   += pml[(base + i)*4 + j];
        acc += pout[(base + i)*512 + j*HD + d];
    }
    attn_out[b*QCOLS + qh*HD + d] = acc / L;
}

// ---------------------------------------------------------------------------
// Final split-K reduce for wo (float2), f32 output.
// ---------------------------------------------------------------------------
__global__ __launch_bounds__(256) void wo_reduce_kernel(
    const float* __restrict__ part, float* __restrict__ out)
{
    const int g = blockIdx.x*256 + threadIdx.x;   // float2 index, 0..16383
    float sx = 0.f, sy = 0.f;
    #pragma unroll 8
    for (int ky = 0; ky < KSP; ky++) {
        float2 v = *reinterpret_cast<const float2*>(part + (size_t)ky*NB*QCOLS + g*2);
        sx += v.x; sy += v.y;
    }
    *reinterpret_cast<float2*>(out + g*2) = make_float2(sx, sy);
}

extern "C" void kernel_launch(void* const* d_in, const int* in_sizes, int n_in,
                              void* d_out, int out_size, void* d_ws, size_t ws_size,
                              hipStream_t stream)
{
    const float* x  = (const float*)d_in[0];
    // d_in[1] = start_pos (int scalar) = 4095, fixed by the problem.
    const float* fc = (const float*)d_in[2];
    const float* fs = (const float*)d_in[3];
    const float* wq = (const float*)d_in[4];
    const float* wk = (const float*)d_in[5];
    const float* wv = (const float*)d_in[6];
    const float* wo = (const float*)d_in[7];
    const float* K  = (const float*)d_in[8];
    const float* V  = (const float*)d_in[9];

    float* ws     = (float*)d_ws;
    float* q      = ws;                     // 32768
    float* knew   = ws + 32768;             // 8192
    float* vnew   = ws + 40960;             // 8192
    float* attn_o = ws + 49152;             // 32768
    float* qkvp   = ws + 81920;             // 64*8*6144 = 3,145,728
    float* pout   = ws + 3227648;           // 512*512   = 262,144
    float* pml    = ws + 3489792;           // 512*4     = 2,048
    float* wop    = ws + 81920;             // aliases qkvp (time-disjoint)

    // 1. fused QKV projection partials (768 blocks = 3/CU even; cached weights)
    gemv4_kernel<<<dim3(CCOLS/512, KSP), dim3(128), 0, stream>>>(x, wq, wk, wv, qkvp, CCOLS);
    // 2. reduce + RoPE
    qkv_reduce_rope<<<dim3(NB*CCOLS/2/256), dim3(256), 0, stream>>>(qkvp, fc, fs, q, knew, vnew);
    // 3. streaming flash-decode v4-NT (non-temporal K/V)
    attn_stream_kernel<<<dim3(NCHB, NKVH, NB), dim3(256), 0, stream>>>(q, knew, vnew, K, V, pout, pml);
    // 4. combine (plain sums)
    attn_combine_kernel<<<dim3(NQH, NB), dim3(128), 0, stream>>>(pout, pml, attn_o);
    // 5. output projection partials (512 blocks = 2/CU even; cached weights)
    gemv4_kernel<<<dim3(QCOLS/512, KSP), dim3(128), 0, stream>>>(attn_o, wo, wo, wo, wop, QCOLS);
    // 6. final reduce, f32 out
    wo_reduce_kernel<<<dim3(NB*QCOLS/2/256), dim3(256), 0, stream>>>(wop, (float*)d_out);
}